// Round 3
// baseline (283.223 us; speedup 1.0000x reference)
//
#include <hip/hip_runtime.h>

#define BATCH   8
#define HH      512
#define WW      512
#define IMGPIX  (HH * WW)          // 262144 = 1<<18
#define NPIX    (BATCH * IMGPIX)   // 2097152
#define KFAC    60.0f
#define MAX_PAIRS 256
#define WPR     8                  // 64-bit words per 512-px row
#define LDSTR   9                  // padded row stride in words
#define FPSCALE 262144.0           // 2^18 fixed-point scale for i64 reduction

typedef unsigned long long u64;
typedef unsigned int u32;

// ---------------- kernel 1: CE loss + packed binary mask + zero accumulators ----------------
__global__ void prep_kernel(const float* __restrict__ pred, const int* __restrict__ target,
                            float* __restrict__ L, u64* __restrict__ xp,
                            u64* __restrict__ acc64, u32* __restrict__ ticket) {
    int i = blockIdx.x * blockDim.x + threadIdx.x;
    if (i == 0) { acc64[0] = 0ULL; ticket[0] = 0u; }
    if (i >= NPIX) return;
    int b = i >> 18;
    int hw = i & (IMGPIX - 1);
    float p0 = pred[((size_t)(2 * b) << 18) + hw];
    float p1 = pred[((size_t)(2 * b + 1) << 18) + hw];
    float m = fmaxf(p0, p1);
    float lse = m + logf(expf(p0 - m) + expf(p1 - m));
    int t = target[i];
    L[i] = lse - (t ? p1 : p0);            // -log_softmax[target]
    u64 word = __ballot(p1 > p0);          // 64 consecutive pixels per wave
    if ((threadIdx.x & 63) == 0) xp[i >> 6] = word;
}

// ---------------- bit-sliced Zhang-Suen helpers ----------------
#define FA(a,b,c,s,cy) { u64 _x = (a)^(b); (s) = _x^(c); (cy) = ((a)&(b)) | ((c)&_x); }
#define HA(a,b,s,cy)   { (s) = (a)^(b); (cy) = (a)&(b); }

// one substep with active-word tracking; returns changed-word mask for this row.
// Monotonicity argument: ZS only deletes, so if no word in the 3x3 word-neighborhood
// changed during the previous TWO substeps, the same-parity rule sees identical
// inputs and the word is a fixpoint for this substep.
template<int FIRST>
__device__ __forceinline__ u32 zs_substep(u64* __restrict__ img,
                                          const u32* __restrict__ c0,
                                          const u32* __restrict__ c1,
                                          u32* __restrict__ cw, int h)
{
    u32 m = c0[h] | c1[h];
    if (h > 0)      m |= c0[h-1] | c1[h-1];
    if (h < HH-1)   m |= c0[h+1] | c1[h+1];
    u32 active = (m | (m << 1) | (m >> 1)) & 0xFFu;
    u32 loadm  = (active | (active << 1) | (active >> 1)) & 0xFFu;

    u64 U[WPR], M[WPR], D[WPR], nrow[WPR];
    #pragma unroll
    for (int wc = 0; wc < WPR; ++wc) {
        if ((loadm >> wc) & 1) {
            U[wc] = (h > 0)      ? img[(h-1) * LDSTR + wc] : 0ULL;
            M[wc] =                img[h     * LDSTR + wc];
            D[wc] = (h < HH - 1) ? img[(h+1) * LDSTR + wc] : 0ULL;
        } else { U[wc] = 0ULL; M[wc] = 0ULL; D[wc] = 0ULL; }
    }
    __syncthreads();   // all reads done before in-place writes

    u32 chnew = 0;
    #pragma unroll
    for (int wc = 0; wc < WPR; ++wc) {
        if ((active >> wc) & 1) {
            u64 Uc = U[wc], Mc = M[wc], Dc = D[wc];
            u64 Up = wc     ? U[wc-1] : 0ULL;
            u64 Mp = wc     ? M[wc-1] : 0ULL;
            u64 Dp = wc     ? D[wc-1] : 0ULL;
            u64 Un = wc < 7 ? U[wc+1] : 0ULL;
            u64 Mn = wc < 7 ? M[wc+1] : 0ULL;
            u64 Dn = wc < 7 ? D[wc+1] : 0ULL;
            u64 P2 = Uc;
            u64 P6 = Dc;
            u64 P3 = (Uc >> 1) | (Un << 63);
            u64 P4 = (Mc >> 1) | (Mn << 63);
            u64 P5 = (Dc >> 1) | (Dn << 63);
            u64 P9 = (Uc << 1) | (Up >> 63);
            u64 P8 = (Mc << 1) | (Mp >> 63);
            u64 P7 = (Dc << 1) | (Dp >> 63);

            u64 sa,ca, sb,cb, sc,cc, b0,cd, sd,ce, b1,cf, b2,b3;
            FA(P2,P3,P4, sa,ca);
            FA(P5,P6,P7, sb,cb);
            FA(P8,P9,sa, sc,cc);
            HA(sb,sc,    b0,cd);
            FA(ca,cb,cc, sd,ce);
            HA(sd,cd,    b1,cf);
            HA(ce,cf,    b2,b3);
            u64 ge2 = b1 | b2 | b3;
            u64 le6 = ~(b3 | (b0 & b1 & b2));

            u64 e, seen, two = 0;
            seen = (~P2) & P3;
            e = (~P3) & P4; two |= seen & e; seen |= e;
            e = (~P4) & P5; two |= seen & e; seen |= e;
            e = (~P5) & P6; two |= seen & e; seen |= e;
            e = (~P6) & P7; two |= seen & e; seen |= e;
            e = (~P7) & P8; two |= seen & e; seen |= e;
            e = (~P8) & P9; two |= seen & e; seen |= e;
            e = (~P9) & P2; two |= seen & e; seen |= e;
            u64 A1 = seen & ~two;

            u64 c34;
            if (FIRST) { u64 t = P4 & P6; c34 = t & (P2 | P8); }
            else       { u64 t = P2 & P8; c34 = t & (P4 | P6); }

            u64 del = Mc & ge2 & le6 & A1 & ~c34;
            nrow[wc] = Mc ^ del;
            chnew |= (u32)(del != 0ULL) << wc;
        }
    }
    #pragma unroll
    for (int wc = 0; wc < WPR; ++wc)
        if ((active >> wc) & 1) img[h * LDSTR + wc] = nrow[wc];
    cw[h] = chnew;
    return chnew;      // caller must barrier before next reads
}

// ---------------- kernel 2: skeletonize + endpoints E + 9x9 dilation D (packed) ----------------
__global__ __launch_bounds__(512)
void skel_kernel(const u64* __restrict__ xp, u64* __restrict__ eg, u64* __restrict__ dg)
{
    __shared__ u64 img[HH * LDSTR];    // 36,864 B
    __shared__ u32 chm[2][HH];         //  4,096 B
    const int b = blockIdx.x;
    const int h = threadIdx.x;

    const u64* src = xp + (size_t)b * (HH * WPR);
    #pragma unroll
    for (int wc = 0; wc < WPR; ++wc) img[h * LDSTR + wc] = src[h * WPR + wc];
    chm[0][h] = 0xFFu; chm[1][h] = 0xFFu;
    __syncthreads();

    for (int p = 0; p < MAX_PAIRS; ++p) {
        u32 ch1 = zs_substep<1>(img, chm[0], chm[1], chm[0], h);
        __syncthreads();
        u32 ch2 = zs_substep<0>(img, chm[0], chm[1], chm[1], h);
        if (!__syncthreads_or((ch1 | ch2) != 0)) break;   // pair deleted nothing anywhere
    }

    // ---- endpoints E = skel & (neighbor count == 1), in registers
    u64 U[WPR], M[WPR], D[WPR], E[WPR];
    #pragma unroll
    for (int wc = 0; wc < WPR; ++wc) {
        U[wc] = (h > 0)      ? img[(h-1) * LDSTR + wc] : 0ULL;
        M[wc] =                img[h     * LDSTR + wc];
        D[wc] = (h < HH - 1) ? img[(h+1) * LDSTR + wc] : 0ULL;
    }
    __syncthreads();
    #pragma unroll
    for (int wc = 0; wc < WPR; ++wc) {
        u64 Uc = U[wc], Mc = M[wc], Dc = D[wc];
        u64 Up = wc     ? U[wc-1] : 0ULL;
        u64 Mp = wc     ? M[wc-1] : 0ULL;
        u64 Dp = wc     ? D[wc-1] : 0ULL;
        u64 Un = wc < 7 ? U[wc+1] : 0ULL;
        u64 Mn = wc < 7 ? M[wc+1] : 0ULL;
        u64 Dn = wc < 7 ? D[wc+1] : 0ULL;
        u64 P2 = Uc;
        u64 P6 = Dc;
        u64 P3 = (Uc >> 1) | (Un << 63);
        u64 P4 = (Mc >> 1) | (Mn << 63);
        u64 P5 = (Dc >> 1) | (Dn << 63);
        u64 P9 = (Uc << 1) | (Up >> 63);
        u64 P8 = (Mc << 1) | (Mp >> 63);
        u64 P7 = (Dc << 1) | (Dp >> 63);
        u64 e, seen, two = 0;
        seen = P2;
        e = P3; two |= seen & e; seen |= e;
        e = P4; two |= seen & e; seen |= e;
        e = P5; two |= seen & e; seen |= e;
        e = P6; two |= seen & e; seen |= e;
        e = P7; two |= seen & e; seen |= e;
        e = P8; two |= seen & e; seen |= e;
        e = P9; two |= seen & e; seen |= e;
        E[wc] = Mc & seen & ~two;       // exactly one neighbor
    }
    // overwrite img with E (skeleton no longer needed)
    #pragma unroll
    for (int wc = 0; wc < WPR; ++wc) img[h * LDSTR + wc] = E[wc];
    __syncthreads();

    // ---- D = 9x9 dilation of E: vertical OR of 9 rows, then horizontal +-4 shift-OR
    u64 Vor[WPR];
    #pragma unroll
    for (int wc = 0; wc < WPR; ++wc) Vor[wc] = 0ULL;
    #pragma unroll
    for (int dh = -4; dh <= 4; ++dh) {
        int hh = h + dh;
        if ((unsigned)hh < (unsigned)HH) {
            #pragma unroll
            for (int wc = 0; wc < WPR; ++wc) Vor[wc] |= img[hh * LDSTR + wc];
        }
    }
    u64* egr = eg + (size_t)b * (HH * WPR) + (size_t)h * WPR;
    u64* dgr = dg + (size_t)b * (HH * WPR) + (size_t)h * WPR;
    #pragma unroll
    for (int wc = 0; wc < WPR; ++wc) {
        u64 v  = Vor[wc];
        u64 vp = wc     ? Vor[wc-1] : 0ULL;
        u64 vn = wc < 7 ? Vor[wc+1] : 0ULL;
        u64 d  = v;
        #pragma unroll
        for (int s = 1; s <= 4; ++s)
            d |= (v >> s) | (vn << (64 - s)) | (v << s) | (vp >> (64 - s));
        egr[wc] = E[wc];
        dgr[wc] = d;
    }
}

// ---------------- kernel 3: weighted sum, deterministic i64 fixed-point, last-block finish ----------------
// sum = Sigma L_i*(1-D_i) + 60 * Sigma_{endpoints e} box9x9(L)(e)
__global__ void final_kernel(const float* __restrict__ L, const u64* __restrict__ eg,
                             const u64* __restrict__ dg, u64* __restrict__ acc64,
                             u32* __restrict__ ticket, float* __restrict__ out) {
    __shared__ float sm[256];
    int i = blockIdx.x * blockDim.x + threadIdx.x;
    int word = i >> 6, bit = i & 63;
    u64 Ew = eg[word], Dw = dg[word];
    float acc = ((Dw >> bit) & 1) ? 0.0f : L[i];
    if ((Ew >> bit) & 1) {                       // sparse: gather 9x9 box of L
        int b = i >> 18, h = (i >> 9) & (HH - 1), w = i & (WW - 1);
        float s = 0.0f;
        for (int dh = -4; dh <= 4; ++dh) {
            int hh = h + dh;
            if ((unsigned)hh >= (unsigned)HH) continue;
            const float* row = L + (size_t)(b << 18) + (hh << 9);
            #pragma unroll
            for (int dw = -4; dw <= 4; ++dw) {
                int ww = w + dw;
                if ((unsigned)ww < (unsigned)WW) s += row[ww];
            }
        }
        acc += KFAC * s;
    }
    sm[threadIdx.x] = acc;
    __syncthreads();
    for (int s = 128; s > 0; s >>= 1) {
        if (threadIdx.x < s) sm[threadIdx.x] += sm[threadIdx.x + s];
        __syncthreads();
    }
    if (threadIdx.x == 0) {
        u64 v = (u64)(long long)llrintf(sm[0] * (float)FPSCALE);
        atomicAdd(acc64, v);
        __threadfence();
        u32 t = atomicAdd(ticket, 1u);
        if (t == (u32)(gridDim.x - 1)) {         // last block finishes
            __threadfence();
            u64 total = __hip_atomic_load(acc64, __ATOMIC_RELAXED, __HIP_MEMORY_SCOPE_AGENT);
            out[0] = (float)((double)(long long)total / (FPSCALE * (double)NPIX));
        }
    }
}

extern "C" void kernel_launch(void* const* d_in, const int* in_sizes, int n_in,
                              void* d_out, int out_size, void* d_ws, size_t ws_size,
                              hipStream_t stream) {
    const float* pred = (const float*)d_in[0];
    const int* target = (const int*)d_in[1];
    float* out = (float*)d_out;
    char* ws = (char*)d_ws;

    // ws layout (bytes):
    //   [0,        8388608)  L       float[NPIX]
    //   [8388608,  8650752)  xp      u64[NPIX/64]  packed mask
    //   [8650752,  8912896)  eg      u64[NPIX/64]  packed endpoints
    //   [8912896,  9175040)  dg      u64[NPIX/64]  packed 9x9 dilation
    //   [9175040,  9175048)  acc64   u64
    //   [9175048,  9175052)  ticket  u32
    float* L   = (float*)(ws);
    u64* xp    = (u64*)(ws + 8388608);
    u64* eg    = (u64*)(ws + 8650752);
    u64* dg    = (u64*)(ws + 8912896);
    u64* acc64 = (u64*)(ws + 9175040);
    u32* ticket= (u32*)(ws + 9175048);

    dim3 blk(256);
    dim3 grd(NPIX / 256);   // 8192 blocks

    prep_kernel<<<grd, blk, 0, stream>>>(pred, target, L, xp, acc64, ticket);
    skel_kernel<<<dim3(BATCH), dim3(512), 0, stream>>>(xp, eg, dg);
    final_kernel<<<grd, blk, 0, stream>>>(L, eg, dg, acc64, ticket, out);
}

// Round 4
// 62.015 us; speedup vs baseline: 4.5670x; 4.5670x over previous
//
#include <hip/hip_runtime.h>

#define BATCH   8
#define HH      512
#define WW      512
#define IMGPIX  (HH * WW)          // 262144 = 1<<18
#define NPIX    (BATCH * IMGPIX)   // 2097152
#define NWORDS  (NPIX / 64)        // 32768 packed words
#define KFAC    60.0f
#define MAX_PAIRS 256
#define WPR     8                  // 64-bit words per 512-px row
#define LDSTR   9                  // padded row stride in words
#define FPSCALE 262144.0           // 2^18 fixed-point scale for i64 reduction

typedef unsigned long long u64;
typedef unsigned int u32;

// ---------------- kernel 1: CE loss + packed binary mask + zero accumulators ----------------
__global__ void prep_kernel(const float* __restrict__ pred, const int* __restrict__ target,
                            float* __restrict__ L, u64* __restrict__ xp,
                            u64* __restrict__ acc64, u32* __restrict__ ticket) {
    int i = blockIdx.x * blockDim.x + threadIdx.x;
    if (i == 0) { acc64[0] = 0ULL; ticket[0] = 0u; }
    if (i >= NPIX) return;
    int b = i >> 18;
    int hw = i & (IMGPIX - 1);
    float p0 = pred[((size_t)(2 * b) << 18) + hw];
    float p1 = pred[((size_t)(2 * b + 1) << 18) + hw];
    float m = fmaxf(p0, p1);
    float lse = m + logf(expf(p0 - m) + expf(p1 - m));
    int t = target[i];
    L[i] = lse - (t ? p1 : p0);            // -log_softmax[target]
    u64 word = __ballot(p1 > p0);          // 64 consecutive pixels per wave
    if ((threadIdx.x & 63) == 0) xp[i >> 6] = word;
}

// ---------------- bit-sliced Zhang-Suen helpers ----------------
#define FA(a,b,c,s,cy) { u64 _x = (a)^(b); (s) = _x^(c); (cy) = ((a)&(b)) | ((c)&_x); }
#define HA(a,b,s,cy)   { (s) = (a)^(b); (cy) = (a)&(b); }

// one substep with active-word tracking; returns changed-word mask for this row.
template<int FIRST>
__device__ __forceinline__ u32 zs_substep(u64* __restrict__ img,
                                          const u32* __restrict__ c0,
                                          const u32* __restrict__ c1,
                                          u32* __restrict__ cw, int h)
{
    u32 m = c0[h] | c1[h];
    if (h > 0)      m |= c0[h-1] | c1[h-1];
    if (h < HH-1)   m |= c0[h+1] | c1[h+1];
    u32 active = (m | (m << 1) | (m >> 1)) & 0xFFu;
    u32 loadm  = (active | (active << 1) | (active >> 1)) & 0xFFu;

    u64 U[WPR], M[WPR], D[WPR], nrow[WPR];
    #pragma unroll
    for (int wc = 0; wc < WPR; ++wc) {
        if ((loadm >> wc) & 1) {
            U[wc] = (h > 0)      ? img[(h-1) * LDSTR + wc] : 0ULL;
            M[wc] =                img[h     * LDSTR + wc];
            D[wc] = (h < HH - 1) ? img[(h+1) * LDSTR + wc] : 0ULL;
        } else { U[wc] = 0ULL; M[wc] = 0ULL; D[wc] = 0ULL; }
    }
    __syncthreads();   // all reads done before in-place writes

    u32 chnew = 0;
    #pragma unroll
    for (int wc = 0; wc < WPR; ++wc) {
        if ((active >> wc) & 1) {
            u64 Uc = U[wc], Mc = M[wc], Dc = D[wc];
            u64 Up = wc     ? U[wc-1] : 0ULL;
            u64 Mp = wc     ? M[wc-1] : 0ULL;
            u64 Dp = wc     ? D[wc-1] : 0ULL;
            u64 Un = wc < 7 ? U[wc+1] : 0ULL;
            u64 Mn = wc < 7 ? M[wc+1] : 0ULL;
            u64 Dn = wc < 7 ? D[wc+1] : 0ULL;
            u64 P2 = Uc;
            u64 P6 = Dc;
            u64 P3 = (Uc >> 1) | (Un << 63);
            u64 P4 = (Mc >> 1) | (Mn << 63);
            u64 P5 = (Dc >> 1) | (Dn << 63);
            u64 P9 = (Uc << 1) | (Up >> 63);
            u64 P8 = (Mc << 1) | (Mp >> 63);
            u64 P7 = (Dc << 1) | (Dp >> 63);

            u64 sa,ca, sb,cb, sc,cc, b0,cd, sd,ce, b1,cf, b2,b3;
            FA(P2,P3,P4, sa,ca);
            FA(P5,P6,P7, sb,cb);
            FA(P8,P9,sa, sc,cc);
            HA(sb,sc,    b0,cd);
            FA(ca,cb,cc, sd,ce);
            HA(sd,cd,    b1,cf);
            HA(ce,cf,    b2,b3);
            u64 ge2 = b1 | b2 | b3;
            u64 le6 = ~(b3 | (b0 & b1 & b2));

            u64 e, seen, two = 0;
            seen = (~P2) & P3;
            e = (~P3) & P4; two |= seen & e; seen |= e;
            e = (~P4) & P5; two |= seen & e; seen |= e;
            e = (~P5) & P6; two |= seen & e; seen |= e;
            e = (~P6) & P7; two |= seen & e; seen |= e;
            e = (~P7) & P8; two |= seen & e; seen |= e;
            e = (~P8) & P9; two |= seen & e; seen |= e;
            e = (~P9) & P2; two |= seen & e; seen |= e;
            u64 A1 = seen & ~two;

            u64 c34;
            if (FIRST) { u64 t = P4 & P6; c34 = t & (P2 | P8); }
            else       { u64 t = P2 & P8; c34 = t & (P4 | P6); }

            u64 del = Mc & ge2 & le6 & A1 & ~c34;
            nrow[wc] = Mc ^ del;
            chnew |= (u32)(del != 0ULL) << wc;
        }
    }
    #pragma unroll
    for (int wc = 0; wc < WPR; ++wc)
        if ((active >> wc) & 1) img[h * LDSTR + wc] = nrow[wc];
    cw[h] = chnew;
    return chnew;      // caller must barrier before next reads
}

// ---------------- kernel 2: skeletonize + packed endpoint map E ----------------
__global__ __launch_bounds__(512)
void skel_kernel(const u64* __restrict__ xp, u64* __restrict__ eg)
{
    __shared__ u64 img[HH * LDSTR];    // 36,864 B
    __shared__ u32 chm[2][HH];         //  4,096 B
    const int b = blockIdx.x;
    const int h = threadIdx.x;

    const u64* src = xp + (size_t)b * (HH * WPR);
    #pragma unroll
    for (int wc = 0; wc < WPR; ++wc) img[h * LDSTR + wc] = src[h * WPR + wc];
    chm[0][h] = 0xFFu; chm[1][h] = 0xFFu;
    __syncthreads();

    for (int p = 0; p < MAX_PAIRS; ++p) {
        u32 ch1 = zs_substep<1>(img, chm[0], chm[1], chm[0], h);
        __syncthreads();
        u32 ch2 = zs_substep<0>(img, chm[0], chm[1], chm[1], h);
        if (!__syncthreads_or((ch1 | ch2) != 0)) break;   // pair deleted nothing anywhere
    }

    // ---- endpoints E = skel & (exactly one 8-neighbor)
    u64 U[WPR], M[WPR], D[WPR];
    #pragma unroll
    for (int wc = 0; wc < WPR; ++wc) {
        U[wc] = (h > 0)      ? img[(h-1) * LDSTR + wc] : 0ULL;
        M[wc] =                img[h     * LDSTR + wc];
        D[wc] = (h < HH - 1) ? img[(h+1) * LDSTR + wc] : 0ULL;
    }
    u64* egr = eg + (size_t)b * (HH * WPR) + (size_t)h * WPR;
    #pragma unroll
    for (int wc = 0; wc < WPR; ++wc) {
        u64 Uc = U[wc], Mc = M[wc], Dc = D[wc];
        u64 Up = wc     ? U[wc-1] : 0ULL;
        u64 Mp = wc     ? M[wc-1] : 0ULL;
        u64 Dp = wc     ? D[wc-1] : 0ULL;
        u64 Un = wc < 7 ? U[wc+1] : 0ULL;
        u64 Mn = wc < 7 ? M[wc+1] : 0ULL;
        u64 Dn = wc < 7 ? D[wc+1] : 0ULL;
        u64 P2 = Uc;
        u64 P6 = Dc;
        u64 P3 = (Uc >> 1) | (Un << 63);
        u64 P4 = (Mc >> 1) | (Mn << 63);
        u64 P5 = (Dc >> 1) | (Dn << 63);
        u64 P9 = (Uc << 1) | (Up >> 63);
        u64 P8 = (Mc << 1) | (Mp >> 63);
        u64 P7 = (Dc << 1) | (Dp >> 63);
        u64 e, seen, two = 0;
        seen = P2;
        e = P3; two |= seen & e; seen |= e;
        e = P4; two |= seen & e; seen |= e;
        e = P5; two |= seen & e; seen |= e;
        e = P6; two |= seen & e; seen |= e;
        e = P7; two |= seen & e; seen |= e;
        e = P8; two |= seen & e; seen |= e;
        e = P9; two |= seen & e; seen |= e;
        egr[wc] = Mc & seen & ~two;       // exactly one neighbor
    }
}

// ---------------- packed-count helpers for final kernel ----------------
struct Planes { u64 p0, p1, p2, p3; };

// bit-sliced sum of 9 one-bit rows -> 4 bitplanes (per-column counts 0..9)
__device__ __forceinline__ Planes vcount9(const u64 r[9]) {
    u64 s0,c0, s1,c1, s2,c2, p0,t0, t1,t2, p1,t3, p2,p3;
    FA(r[0],r[1],r[2], s0,c0);
    FA(r[3],r[4],r[5], s1,c1);
    FA(r[6],r[7],r[8], s2,c2);
    FA(s0,s1,s2, p0,t0);       // t0 weight 2
    FA(c0,c1,c2, t1,t2);       // t1 w2, t2 w4
    HA(t0,t1,    p1,t3);       // t3 w4
    HA(t2,t3,    p2,p3);
    Planes P; P.p0 = p0; P.p1 = p1; P.p2 = p2; P.p3 = p3; return P;
}

// spread 8 bits -> 8 bytes (0/1 each)
__device__ __forceinline__ u64 spread8(u64 bb) {
    u64 s = (bb * 0x0101010101010101ULL) & 0x8040201008040201ULL;
    return ((s + 0x7f7f7f7f7f7f7f7fULL) >> 7) & 0x0101010101010101ULL;
}

// byte-packed vertical counts for 8 consecutive columns (group g of a word)
__device__ __forceinline__ u64 vbytes(const Planes& P, int g) {
    int s = 8 * g;
    return  spread8((P.p0 >> s) & 0xFFULL)
         + (spread8((P.p1 >> s) & 0xFFULL) << 1)
         + (spread8((P.p2 >> s) & 0xFFULL) << 2)
         + (spread8((P.p3 >> s) & 0xFFULL) << 3);
}

// ---------------- kernel 3: dense weighted sum ----------------
// w_i = 60*n_i + [n_i==0], n_i = 9x9 box count of E;  out = mean(w*L)
__global__ __launch_bounds__(256)
void final_kernel(const float* __restrict__ L, const u64* __restrict__ eg,
                  u64* __restrict__ acc64, u32* __restrict__ ticket,
                  float* __restrict__ out) {
    __shared__ float sm[256];
    int wi = blockIdx.x * blockDim.x + threadIdx.x;   // word index, 32768 total
    int b  = wi >> 12;                                // 4096 words / image
    int h  = (wi >> 3) & (HH - 1);
    int wc = wi & 7;
    const u64* img = eg + ((size_t)b << 12);

    // load 9 rows x 3 word-columns of E (zero outside)
    u64 rows[3][9];
    #pragma unroll
    for (int dh = -4; dh <= 4; ++dh) {
        int hh = h + dh;
        bool okh = (unsigned)hh < (unsigned)HH;
        const u64* rp = img + hh * WPR;
        rows[0][dh + 4] = (okh && wc > 0) ? rp[wc - 1] : 0ULL;
        rows[1][dh + 4] = okh             ? rp[wc]     : 0ULL;
        rows[2][dh + 4] = (okh && wc < 7) ? rp[wc + 1] : 0ULL;
    }
    Planes Pm = vcount9(rows[0]);
    Planes Pc = vcount9(rows[1]);
    Planes Pp = vcount9(rows[2]);

    // byte-packed vertical counts for groups -1..8 (v[0]=group -1, v[9]=group 8)
    u64 v[10];
    v[0] = vbytes(Pm, 7);
    #pragma unroll
    for (int g = 0; g < 8; ++g) v[g + 1] = vbytes(Pc, g);
    v[9] = vbytes(Pp, 0);

    // horizontal 9-window byte sums + weighted accumulate against L
    const float4* Lr = (const float4*)(L + ((size_t)wi << 6));
    float acc = 0.0f;
    #pragma unroll
    for (int g = 0; g < 8; ++g) {
        u64 a = v[g + 1], lo = v[g], hi = v[g + 2];
        u64 n = a;
        #pragma unroll
        for (int d = 1; d <= 4; ++d) {
            n += (a >> (8 * d)) | (hi << (64 - 8 * d));
            n += (a << (8 * d)) | (lo >> (64 - 8 * d));
        }
        float4 f0 = Lr[2 * g], f1 = Lr[2 * g + 1];
        #pragma unroll
        for (int j = 0; j < 8; ++j) {
            int cnt = (int)((n >> (8 * j)) & 0xFFULL);
            float wgt = cnt ? (float)(60 * cnt) : 1.0f;
            float lv = (j < 4) ? ((j == 0) ? f0.x : (j == 1) ? f0.y : (j == 2) ? f0.z : f0.w)
                               : ((j == 4) ? f1.x : (j == 5) ? f1.y : (j == 6) ? f1.z : f1.w);
            acc += wgt * lv;
        }
    }

    sm[threadIdx.x] = acc;
    __syncthreads();
    for (int s = 128; s > 0; s >>= 1) {
        if (threadIdx.x < s) sm[threadIdx.x] += sm[threadIdx.x + s];
        __syncthreads();
    }
    if (threadIdx.x == 0) {
        u64 vfx = (u64)(long long)llrintf(sm[0] * (float)FPSCALE);
        atomicAdd(acc64, vfx);
        __threadfence();
        u32 t = atomicAdd(ticket, 1u);
        if (t == (u32)(gridDim.x - 1)) {           // last block finishes
            __threadfence();
            u64 total = __hip_atomic_load(acc64, __ATOMIC_RELAXED, __HIP_MEMORY_SCOPE_AGENT);
            out[0] = (float)((double)(long long)total / (FPSCALE * (double)NPIX));
        }
    }
}

extern "C" void kernel_launch(void* const* d_in, const int* in_sizes, int n_in,
                              void* d_out, int out_size, void* d_ws, size_t ws_size,
                              hipStream_t stream) {
    const float* pred = (const float*)d_in[0];
    const int* target = (const int*)d_in[1];
    float* out = (float*)d_out;
    char* ws = (char*)d_ws;

    // ws layout (bytes):
    //   [0,        8388608)  L       float[NPIX]
    //   [8388608,  8650752)  xp      u64[NWORDS]  packed mask
    //   [8650752,  8912896)  eg      u64[NWORDS]  packed endpoints
    //   [8912896,  8912904)  acc64   u64
    //   [8912904,  8912908)  ticket  u32
    float* L    = (float*)(ws);
    u64* xp     = (u64*)(ws + 8388608);
    u64* eg     = (u64*)(ws + 8650752);
    u64* acc64  = (u64*)(ws + 8912896);
    u32* ticket = (u32*)(ws + 8912904);

    prep_kernel<<<dim3(NPIX / 256), dim3(256), 0, stream>>>(pred, target, L, xp, acc64, ticket);
    skel_kernel<<<dim3(BATCH), dim3(512), 0, stream>>>(xp, eg);
    final_kernel<<<dim3(NWORDS / 256), dim3(256), 0, stream>>>(L, eg, acc64, ticket, out);
}